// Round 2
// 313.103 us; speedup vs baseline: 1.0351x; 1.0351x over previous
//
#include <hip/hip_runtime.h>

// LIF neuron scan: 16384 neurons x 2048 sequential steps, 1 thread/neuron,
// 256 waves = 1 wave/CU (structural).
//
// R3 (register ring) was vmcnt-capped: 6-bit vmcnt => <=63 outstanding VMEM
// ops/wave; at 256 B per dword-load instruction the chip-wide in-flight byte
// ceiling is 256 waves x 63 x 256 B ~= 4 MB => ~3.8 TB/s effective (matches
// 402 MB / 106 us). Re-tiling neurons/thread doesn't change the product.
//
// R4: raise bytes-per-vmcnt-slot 4x via global_load_lds_dwordx4 (1 KB/instr,
// per-lane global addrs: lane l -> row t+(l>>4), cols 4*(l&15); LDS dest is
// linear [4][64]). LDS ring R=16 slots x 2 KB (I+Z), prefetch distance P=14
// chunks => 26 KB loads in flight/wave at only 39 vmcnt slots. Counted waits
// (asm s_waitcnt vmcnt(K), steady K=3*(P-1)=39, never 0) with exact ramps in
// prologue/epilogue; waits are conservative-safe if the compiler emits MORE
// vmem instrs than modeled (in-order vmcnt retire => smaller K is always
// correct). Spikes transpose through a 1 KB LDS buffer so each chunk's output
// is ONE float4 NT store (keeps vmem at 3 instrs/stage: 2 DMA + 1 store).
//
// R5 fix: __builtin_nontemporal_store requires a native ext_vector type,
// not HIP's float4 class -> use ext_vector_type(4) for LDS read + NT store.
//
// Exactness (binary spike output): contract(off), reference op order:
//   V = (V + 0.05f*(I-V)) + nz ; s = V>=Vth ; V = s?0:V ;
//   Vth = s ? min(max(Vth+0.1f,0.5f),2.0f) : Vth

constexpr int N = 16384;    // neurons
constexpr int T = 2048;     // sequential steps
constexpr int U = 4;        // timesteps per chunk (one 1KB DMA per stream)
constexpr int C = T / U;    // 512 chunks
constexpr int R = 16;       // LDS ring slots (32 KB payload)
constexpr int P = 14;       // prefetch distance in chunks (26 KB in flight)

static_assert(C == 512 && R == 16 && P <= R - 2, "schedule geometry");

typedef float f4v __attribute__((ext_vector_type(4)));

__device__ __forceinline__ void dma16(const float* g, float* l) {
    __builtin_amdgcn_global_load_lds(
        (const __attribute__((address_space(1))) void*)g,
        (__attribute__((address_space(3))) void*)l, 16, 0, 0);
}

#define WAITV(K) asm volatile("s_waitcnt vmcnt(" #K ")" ::: "memory")

__global__
__attribute__((amdgpu_flat_work_group_size(64, 64)))
void TorchLIFNeuronGroup_85152021610615_kernel(const float* __restrict__ I,
                                               const float* __restrict__ Z,
                                               float* __restrict__ O) {
    #pragma clang fp contract(off)
    // ring[slot][stream][row][neuron] ; each (slot,stream) chunk is one
    // contiguous 1 KB DMA destination (lane*16B linear).
    __shared__ __align__(16) float ring[R][2][U][64];
    __shared__ __align__(16) float sbuf[U][64];   // spike transpose buffer

    const int lane = threadIdx.x;
    const int g    = lane >> 4;          // row within chunk (0..3)
    const int c4   = (lane & 15) << 2;   // col group (0,4,..,60)
    const size_t laneOff = (size_t)g * N + c4;

    const float* ipfx = I + (size_t)blockIdx.x * 64 + laneOff;
    const float* zpfx = Z + (size_t)blockIdx.x * 64 + laneOff;
    float*       opfx = O + (size_t)blockIdx.x * 64 + laneOff;

    float V   = 0.0f;   // V_RESET
    float Vth = 1.0f;   // V_TH0

    // Prologue: DMA chunks 0..P-1 into slots 0..P-1 (chunk-major order).
    #pragma unroll
    for (int c = 0; c < P; ++c) {
        dma16(ipfx + (size_t)(c * U) * N, &ring[c][0][0][0]);
        dma16(zpfx + (size_t)(c * U) * N, &ring[c][1][0][0]);
    }

    int t = 0;  // timestep base of the chunk being computed

    // Stage: wait (counted) -> compute 4 steps from LDS -> spike transpose ->
    // one float4 NT store -> prefetch chunk t/U+P into slot (d+P)%R.
    // Steady-state vmem per stage = 2 DMA + 1 store = 3.
#define STAGE(d, K, PF)                                                       \
    {                                                                         \
        WAITV(K);                                                             \
        _Pragma("unroll")                                                     \
        for (int u = 0; u < U; ++u) {                                         \
            float Iv = ring[d][0][u][lane];                                   \
            float Zv = ring[d][1][u][lane];                                   \
            float dd = Iv - V;                                                \
            float v1 = V + 0.05f * dd;          /* DT/TAU */                  \
            float v2 = v1 + Zv;                                               \
            bool  s  = (v2 >= Vth);                                           \
            V = s ? 0.0f : v2;                                                \
            float nth = fminf(fmaxf(Vth + 0.1f, 0.5f), 2.0f);                 \
            Vth = s ? nth : Vth;                                              \
            sbuf[u][lane] = s ? 1.0f : 0.0f;                                  \
        }                                                                     \
        {                                                                     \
            f4v sv = *reinterpret_cast<const f4v*>(&sbuf[g][c4]);             \
            __builtin_nontemporal_store(                                      \
                sv, reinterpret_cast<f4v*>(opfx + (size_t)t * N));            \
        }                                                                     \
        if (PF) {                                                             \
            dma16(ipfx + (size_t)(t + P * U) * N,                             \
                  &ring[(d + P) & (R - 1)][0][0][0]);                         \
            dma16(zpfx + (size_t)(t + P * U) * N,                             \
                  &ring[(d + P) & (R - 1)][1][0][0]);                         \
        }                                                                     \
        __builtin_amdgcn_sched_barrier(0);                                    \
        t += U;                                                               \
    }

    // Iteration 0 (stages 0..15): ramped waits K(s) = 26+s up to steady 39.
    STAGE(0, 26, 1)  STAGE(1, 27, 1)  STAGE(2, 28, 1)  STAGE(3, 29, 1)
    STAGE(4, 30, 1)  STAGE(5, 31, 1)  STAGE(6, 32, 1)  STAGE(7, 33, 1)
    STAGE(8, 34, 1)  STAGE(9, 35, 1)  STAGE(10, 36, 1) STAGE(11, 37, 1)
    STAGE(12, 38, 1) STAGE(13, 39, 1) STAGE(14, 39, 1) STAGE(15, 39, 1)

    // Steady iterations 1..30 (stages 16..495): all K=39, all prefetch.
    for (int it = 1; it <= 30; ++it) {
        STAGE(0, 39, 1)  STAGE(1, 39, 1)  STAGE(2, 39, 1)  STAGE(3, 39, 1)
        STAGE(4, 39, 1)  STAGE(5, 39, 1)  STAGE(6, 39, 1)  STAGE(7, 39, 1)
        STAGE(8, 39, 1)  STAGE(9, 39, 1)  STAGE(10, 39, 1) STAGE(11, 39, 1)
        STAGE(12, 39, 1) STAGE(13, 39, 1) STAGE(14, 39, 1) STAGE(15, 39, 1)
    }

    // Last iteration (stages 496..511): prefetch stops at chunk 511 (stage
    // 497); waits ramp down exactly: K = 13 + 2*(511 - s) for s >= 498.
    STAGE(0, 39, 1)  STAGE(1, 39, 1)
    STAGE(2, 39, 0)  STAGE(3, 37, 0)  STAGE(4, 35, 0)  STAGE(5, 33, 0)
    STAGE(6, 31, 0)  STAGE(7, 29, 0)  STAGE(8, 27, 0)  STAGE(9, 25, 0)
    STAGE(10, 23, 0) STAGE(11, 21, 0) STAGE(12, 19, 0) STAGE(13, 17, 0)
    STAGE(14, 15, 0) STAGE(15, 13, 0)

#undef STAGE
}

extern "C" void kernel_launch(void* const* d_in, const int* in_sizes, int n_in,
                              void* d_out, int out_size, void* d_ws, size_t ws_size,
                              hipStream_t stream) {
    const float* input_current = (const float*)d_in[0];
    const float* noise         = (const float*)d_in[1];
    float* out                 = (float*)d_out;

    TorchLIFNeuronGroup_85152021610615_kernel<<<N / 64, 64, 0, stream>>>(
        input_current, noise, out);
}